// Round 4
// baseline (29638.608 us; speedup 1.0000x reference)
//
#include <hip/hip_runtime.h>
#include <cstdint>
#include <cstddef>

// ---------------- problem constants ----------------
namespace {
constexpr int Bb = 8, Ss = 2048, Ee = 256, Hh = 256, G4 = 1024, Tt = 12;
constexpr int NTOK = Bb * Ss;              // 16384 rows
constexpr int NC = 256, LCH = 64;          // viterbi chunking: 256 chunks x 64 steps
constexpr float FNEG = -10000.0f;
constexpr int START_TAG = 10, STOP_TAG = 11;

// ---------------- workspace layout (bytes) ----------------
constexpr size_t OFF_XS    = 0;                         // [16384][256] f32 gathered embeddings
constexpr size_t SZ_XS     = (size_t)NTOK * Ee * 4;
constexpr size_t OFF_WT    = OFF_XS + SZ_XS;            // [2][256][1024] f32 w_ih transposed
constexpr size_t SZ_WT     = (size_t)2 * Ee * G4 * 4;
constexpr size_t OFF_XPF   = OFF_WT + SZ_WT;            // [2048][8][1024] f32 x-proj fwd (bias folded)
constexpr size_t SZ_XP     = (size_t)Ss * Bb * G4 * 4;
constexpr size_t OFF_XPB   = OFF_XPF + SZ_XP;
constexpr size_t OFF_HF    = OFF_XPB + SZ_XP;           // [2048][8][256] f32 fwd hidden history
constexpr size_t SZ_H      = (size_t)Ss * Bb * Hh * 4;
constexpr size_t OFF_HB    = OFF_HF + SZ_H;
constexpr size_t OFF_FEATS = OFF_HB + SZ_H;             // [16384][12] f32
constexpr size_t SZ_FEATS  = (size_t)NTOK * Tt * 4;
constexpr size_t OFF_PMAT  = OFF_FEATS + SZ_FEATS;      // [256][144] f32 chunk max-plus mats
constexpr size_t SZ_PMAT   = (size_t)NC * 144 * 4;
constexpr size_t OFF_FVIN  = OFF_PMAT + SZ_PMAT;        // [256][12] f32 chunk-entry fv
constexpr size_t SZ_FVIN   = (size_t)NC * Tt * 4;
constexpr size_t OFF_BPTR  = OFF_FVIN + SZ_FVIN;        // [16384] u64 packed 12x4bit backptrs
constexpr size_t SZ_BPTR   = (size_t)NTOK * 8;
constexpr size_t OFF_CMAP  = OFF_BPTR + SZ_BPTR;        // [256][12] int chunk composed maps
constexpr size_t SZ_CMAP   = (size_t)NC * Tt * 4;
constexpr size_t OFF_EVEC  = OFF_CMAP + SZ_CMAP;        // [256] int tag at chunk-end
constexpr size_t SZ_EVEC   = (size_t)NC * 4;
constexpr size_t OFF_BEST  = OFF_EVEC + SZ_EVEC;        // [1] int
constexpr size_t SZ_BEST   = 256;
constexpr size_t OFF_HD    = OFF_BEST + SZ_BEST;        // (legacy MALL exchange buf, unused)
constexpr size_t SZ_HD     = (size_t)2 * 2 * 2048 * 8;
constexpr size_t OFF_CNT   = OFF_HD + SZ_HD;            // (legacy, unused)
constexpr size_t SZ_CNT    = 256;
constexpr size_t WS_NEED   = OFF_CNT + SZ_CNT;          // ~179 MB (unchanged vs prior rounds)

// R8: per-XCD exchange buffers live INSIDE the feats region (feats is written
// only AFTER k_lstm completes, so the space is dead during the recurrence):
//   xhd: [8 xcd][2 dir][2 par][2048] u64 tagged h   = 512 KB
//   xtk: [8 xcd] u32 arrival tickets, 128B apart    = 1 KB
constexpr size_t OFF_XHD   = OFF_FEATS;
constexpr size_t SZ_XHD    = (size_t)8 * 2 * 2 * 2048 * 8;   // 524288
constexpr size_t OFF_XTK   = OFF_XHD + SZ_XHD;
constexpr size_t SZ_XTK    = 1024;
static_assert(SZ_XHD + SZ_XTK <= SZ_FEATS, "exchange buffers must fit in feats region");

constexpr int POLL_TMO = 1 << 14;   // ~2-3 ms of L2 polls before declaring group dead

__device__ __forceinline__ float4 f4fma(float a, float4 b, float4 c) {
  c.x = fmaf(a, b.x, c.x); c.y = fmaf(a, b.y, c.y);
  c.z = fmaf(a, b.z, c.z); c.w = fmaf(a, b.w, c.w);
  return c;
}

// sum across the 4 lanes of a quad via DPP quad_perm -- VALU pipe only.
__device__ __forceinline__ float quad_sum(float x) {
  float y = __int_as_float(
      __builtin_amdgcn_update_dpp(0, __float_as_int(x), 0xB1, 0xF, 0xF, true));
  x += y;  // + lane^1
  y = __int_as_float(
      __builtin_amdgcn_update_dpp(0, __float_as_int(x), 0x4E, 0xF, 0xF, true));
  return x + y;  // + lane^2
}
__device__ __forceinline__ float4 quad_sum4(float4 v) {
  v.x = quad_sum(v.x); v.y = quad_sum(v.y);
  v.z = quad_sum(v.z); v.w = quad_sum(v.w);
  return v;
}
}  // namespace

// ---------------- init: zero per-XCD tagged exchange buffers + tickets ----------------
// MUST run each launch/graph-replay: tags are step numbers identical across
// runs; stale tags would satisfy polls with old data. Kernel-end flush +
// kernel-begin invalidate make zeros visible to k_lstm's L2-point RMWs.
__global__ __launch_bounds__(256) void k_init(unsigned long long* xhd, unsigned* xtk) {
  int g = blockIdx.x * 256 + threadIdx.x;
  for (int i = g; i < 8 * 8192; i += 32 * 256) xhd[i] = 0ULL;
  if (g < 256) xtk[g] = 0u;
}

// ---------------- gather embeddings: xs[r=t*8+b][k] = emb[sentence[b][t]][k] ----------------
__global__ __launch_bounds__(256) void k_gather(const int* __restrict__ sent,
                                                const float* __restrict__ emb,
                                                float* __restrict__ xs) {
  int rr = threadIdx.x >> 3, p = threadIdx.x & 7;
  int r = blockIdx.x * 32 + rr;
  int tg = r >> 3, bg = r & 7;
  int tok = sent[bg * Ss + tg];
  const float4* src = (const float4*)(emb + (size_t)tok * Ee) + p * 8;
  float4* dst = (float4*)(xs + (size_t)r * Ee) + p * 8;
#pragma unroll
  for (int i = 0; i < 8; ++i) dst[i] = src[i];
}

// ---------------- transpose w_ih -> wT[d][k][n] ----------------
__global__ __launch_bounds__(256) void k_transpose(const float* __restrict__ w_f,
                                                   const float* __restrict__ w_b,
                                                   float* __restrict__ wT) {
  int idx = blockIdx.x * 256 + threadIdx.x;
  if (idx >= 2 * Ee * G4) return;
  int d = idx >> 18;
  int rem = idx & 262143;
  int k = rem >> 10, n = rem & 1023;
  const float* w = d ? w_b : w_f;
  wT[idx] = w[n * Ee + k];
}

// ---------------- input projection GEMM: xp[r][n] = xs[r][:] . w_ih[n][:] + bias[n] ----------------
__global__ __launch_bounds__(256) void k_inproj(const float* __restrict__ xs,
                                                const float* __restrict__ wT,
                                                const float* __restrict__ b_f,
                                                const float* __restrict__ b_b,
                                                float* __restrict__ xpf,
                                                float* __restrict__ xpb) {
  const int dir = blockIdx.z;
  const float* wTd = wT + (size_t)dir * (Ee * G4);
  const float* bv = dir ? b_b : b_f;
  float* xp = dir ? xpb : xpf;
  const int rg = threadIdx.x >> 5, cg = threadIdx.x & 31;
  const int rbase = blockIdx.x * 32 + rg * 4;
  const int c0 = blockIdx.y * 128 + cg * 4;
  const float4* ap0 = (const float4*)(xs + (size_t)(rbase + 0) * Ee);
  const float4* ap1 = (const float4*)(xs + (size_t)(rbase + 1) * Ee);
  const float4* ap2 = (const float4*)(xs + (size_t)(rbase + 2) * Ee);
  const float4* ap3 = (const float4*)(xs + (size_t)(rbase + 3) * Ee);
  float4 acc0 = {0,0,0,0}, acc1 = {0,0,0,0}, acc2 = {0,0,0,0}, acc3 = {0,0,0,0};
#pragma unroll 4
  for (int k4 = 0; k4 < 64; ++k4) {
    float4 a0 = ap0[k4], a1 = ap1[k4], a2 = ap2[k4], a3 = ap3[k4];
    const float* wb = wTd + (size_t)(k4 * 4) * G4 + c0;
    float4 b0 = *(const float4*)(wb);
    float4 b1 = *(const float4*)(wb + G4);
    float4 b2 = *(const float4*)(wb + 2 * G4);
    float4 b3 = *(const float4*)(wb + 3 * G4);
    acc0 = f4fma(a0.x, b0, acc0); acc0 = f4fma(a0.y, b1, acc0);
    acc0 = f4fma(a0.z, b2, acc0); acc0 = f4fma(a0.w, b3, acc0);
    acc1 = f4fma(a1.x, b0, acc1); acc1 = f4fma(a1.y, b1, acc1);
    acc1 = f4fma(a1.z, b2, acc1); acc1 = f4fma(a1.w, b3, acc1);
    acc2 = f4fma(a2.x, b0, acc2); acc2 = f4fma(a2.y, b1, acc2);
    acc2 = f4fma(a2.z, b2, acc2); acc2 = f4fma(a2.w, b3, acc2);
    acc3 = f4fma(a3.x, b0, acc3); acc3 = f4fma(a3.y, b1, acc3);
    acc3 = f4fma(a3.z, b2, acc3); acc3 = f4fma(a3.w, b3, acc3);
  }
  float4 bias = *(const float4*)(bv + c0);
  acc0.x += bias.x; acc0.y += bias.y; acc0.z += bias.z; acc0.w += bias.w;
  acc1.x += bias.x; acc1.y += bias.y; acc1.z += bias.z; acc1.w += bias.w;
  acc2.x += bias.x; acc2.y += bias.y; acc2.z += bias.z; acc2.w += bias.w;
  acc3.x += bias.x; acc3.y += bias.y; acc3.z += bias.z; acc3.w += bias.w;
  *(float4*)(xp + (size_t)(rbase + 0) * G4 + c0) = acc0;
  *(float4*)(xp + (size_t)(rbase + 1) * G4 + c0) = acc1;
  *(float4*)(xp + (size_t)(rbase + 2) * G4 + c0) = acc2;
  *(float4*)(xp + (size_t)(rbase + 3) * G4 + c0) = acc3;
}

// ---------------- persistent bidirectional LSTM recurrence ----------------
// R8: SAME-XCD GROUPS, L2-POINT SYNC.
//   R4/R5/R7 post-mortems: three protocols spanning ~2.5x difference in MALL
//   round-trip count all land at 6.5-6.8us/step => the floor is the per-hop
//   agent-scope (MALL) visibility latency itself, paid serially 2048 times.
//   Fix: move the coherence point to one XCD's L2 (~10x closer).
// Mechanism:
//   - launch 256 blocks; each reads its XCD id via s_getreg hwreg(XCC_ID=20)
//     and takes a ticket on a per-XCD counter (agent scope, startup only).
//   - first 16 blocks OF EACH XCD form a complete worker group (wg 0..7 fwd,
//     8..15 bwd) using that XCD's PRIVATE exchange buffer; others exit.
//     Pigeonhole: >=1 XCD gets >=16 blocks => >=1 complete group. All
//     complete groups compute redundantly and write identical hist (benign).
//   - exchange protocol = R7 tag-in-data ([tag:32|f32:32], parity dbuf), but
//     publishes/polls are WORKGROUP-scope atomics on global memory: these
//     emit global_atomic ops WITHOUT device-scope cache bits => execute at
//     the XCD L2 (coherent for all CUs of the XCD, ~200-400cy instead of
//     multi-us MALL visibility).
//   - polls are fetch_add(slot, ZERO) where ZERO is a KERNEL ARGUMENT so the
//     compiler cannot fold the idempotent RMW into a plain load (a plain
//     load could hit stale L1 and livelock; the RMW always executes at L2).
//   - any WG whose poll exceeds POLL_TMO iterations marks itself dead and
//     exits WITHOUT writing (incomplete/miscoherent groups die cleanly;
//     their partial hist writes were correct duplicates). No hangs.
__global__ __launch_bounds__(512, 2) void k_lstm(
    const float* __restrict__ whh_f, const float* __restrict__ whh_b,
    const float* __restrict__ h0, const float* __restrict__ c0,
    const float* __restrict__ xpf, const float* __restrict__ xpb,
    float* __restrict__ hist_f, float* __restrict__ hist_b,
    unsigned long long* xhd, unsigned* xtk, unsigned long long zero64) {
  __shared__ __align__(16) float h_lds[2048];   // [k][b]
  __shared__ float part[128 * 33];              // [row][ks_hi*8 + b], pad 33
  __shared__ int s_role, s_xcc, wg_dead;

  const int t = threadIdx.x;
  if (t == 0) {
    unsigned xcc = __builtin_amdgcn_s_getreg((3 << 11) | 20) & 7u;  // hwreg(XCC_ID=20,0,4)
    unsigned r = __hip_atomic_fetch_add(xtk + xcc * 32, 1u,
                                        __ATOMIC_RELAXED, __HIP_MEMORY_SCOPE_AGENT);
    s_role = (int)r;
    s_xcc = (int)xcc;
    wg_dead = 0;
  }
  __syncthreads();
  if (s_role >= 16) return;   // uniform block exit
  const int wg = s_role, dir = wg >> 3, j0 = (wg & 7) * 32;
  const float* whh = dir ? whh_b : whh_f;
  const float* xp = dir ? xpb : xpf;
  float* hist = dir ? hist_b : hist_f;
  unsigned long long* hd = xhd + (size_t)s_xcc * 8192 + (size_t)dir * 4096;

  // FMA-thread mapping: lane = rg(16) x ks_lo(4); wave = ks_hi(4) x bs(2)
  const int wave = t >> 6, lane = t & 63;
  const int ks_hi = wave & 3, bs = wave >> 2;   // wave-uniform
  const int rg = lane >> 2, ks_lo = lane & 3;   // per-lane
  // weights: 8 rows x 16 k per thread, k = ks_hi*64 + i*4 + ks_lo
  float wreg[8][16];
#pragma unroll
  for (int r = 0; r < 8; ++r) {
    const int row = rg * 8 + r;
    const int n = ((row >> 5) << 8) + j0 + (row & 31);
    const float* wb = whh + (size_t)n * Hh + ks_hi * 64 + ks_lo;
#pragma unroll
    for (int i = 0; i < 16; ++i) wreg[r][i] = wb[i * 4];
  }
  // gate-thread mapping (t<256): owns hidden unit (j0+jj, batch bg)
  const int jj = t >> 3, bg = t & 7;
  float c_reg = 0.0f;
  if (t < 256) c_reg = c0[dir * 2048 + bg * Hh + j0 + jj];

  for (int s = 0; s < Ss; ++s) {
    const int tg = dir ? (Ss - 1 - s) : s;
    // gate threads prefetch their 4 x-proj values (overlap the wait)
    float xq0 = 0.f, xq1 = 0.f, xq2 = 0.f, xq3 = 0.f;
    if (t < 256) {
      const float* xpt = xp + (size_t)tg * 8192 + bg * G4 + j0 + jj;
      xq0 = xpt[0]; xq1 = xpt[256]; xq2 = xpt[512]; xq3 = xpt[768];
    }
    // fill h_lds[k][b] with h_{s-1}
    if (s == 0) {
#pragma unroll
      for (int i = 0; i < 4; ++i) {
        int idx = t * 4 + i;
        h_lds[idx] = h0[dir * 2048 + (idx & 7) * Hh + (idx >> 3)];
      }
    } else {
      // poll own 4 tagged words at the XCD L2 until tag == s
      unsigned long long* buf = hd + (size_t)((s - 1) & 1) * 2048 + 4 * t;
      const unsigned want = (unsigned)s;
      int to = 0;
      unsigned long long w0, w1, w2, w3;
      w0 = __hip_atomic_fetch_add(buf + 0, zero64, __ATOMIC_RELAXED,
                                  __HIP_MEMORY_SCOPE_WORKGROUP);
      while ((unsigned)(w0 >> 32) != want && ++to < POLL_TMO) {
        __builtin_amdgcn_s_sleep(1);
        w0 = __hip_atomic_fetch_add(buf + 0, zero64, __ATOMIC_RELAXED,
                                    __HIP_MEMORY_SCOPE_WORKGROUP);
      }
      w1 = __hip_atomic_fetch_add(buf + 1, zero64, __ATOMIC_RELAXED,
                                  __HIP_MEMORY_SCOPE_WORKGROUP);
      while ((unsigned)(w1 >> 32) != want && ++to < POLL_TMO) {
        __builtin_amdgcn_s_sleep(1);
        w1 = __hip_atomic_fetch_add(buf + 1, zero64, __ATOMIC_RELAXED,
                                    __HIP_MEMORY_SCOPE_WORKGROUP);
      }
      w2 = __hip_atomic_fetch_add(buf + 2, zero64, __ATOMIC_RELAXED,
                                  __HIP_MEMORY_SCOPE_WORKGROUP);
      while ((unsigned)(w2 >> 32) != want && ++to < POLL_TMO) {
        __builtin_amdgcn_s_sleep(1);
        w2 = __hip_atomic_fetch_add(buf + 2, zero64, __ATOMIC_RELAXED,
                                    __HIP_MEMORY_SCOPE_WORKGROUP);
      }
      w3 = __hip_atomic_fetch_add(buf + 3, zero64, __ATOMIC_RELAXED,
                                  __HIP_MEMORY_SCOPE_WORKGROUP);
      while ((unsigned)(w3 >> 32) != want && ++to < POLL_TMO) {
        __builtin_amdgcn_s_sleep(1);
        w3 = __hip_atomic_fetch_add(buf + 3, zero64, __ATOMIC_RELAXED,
                                    __HIP_MEMORY_SCOPE_WORKGROUP);
      }
      if (to >= POLL_TMO) wg_dead = 1;
      float4 hv4;
      hv4.x = __uint_as_float((unsigned)w0);
      hv4.y = __uint_as_float((unsigned)w1);
      hv4.z = __uint_as_float((unsigned)w2);
      hv4.w = __uint_as_float((unsigned)w3);
      ((float4*)h_lds)[t] = hv4;
    }
    __syncthreads();  // B1: h_lds ready, prev-step part[] reusable
    if (wg_dead) return;  // dead group: exit before writing anything this step
    // recurrent GEMM: 8 rows x 16 k x 4 b per thread
    float4 acc0 = {0,0,0,0}, acc1 = {0,0,0,0}, acc2 = {0,0,0,0}, acc3 = {0,0,0,0};
    float4 acc4 = {0,0,0,0}, acc5 = {0,0,0,0}, acc6 = {0,0,0,0}, acc7 = {0,0,0,0};
    const float* hbase = h_lds + ks_hi * 512 + ks_lo * 8 + bs * 4;
#pragma unroll
    for (int i = 0; i < 16; ++i) {
      float4 h4 = *(const float4*)(hbase + i * 32);
      acc0 = f4fma(wreg[0][i], h4, acc0);
      acc1 = f4fma(wreg[1][i], h4, acc1);
      acc2 = f4fma(wreg[2][i], h4, acc2);
      acc3 = f4fma(wreg[3][i], h4, acc3);
      acc4 = f4fma(wreg[4][i], h4, acc4);
      acc5 = f4fma(wreg[5][i], h4, acc5);
      acc6 = f4fma(wreg[6][i], h4, acc6);
      acc7 = f4fma(wreg[7][i], h4, acc7);
    }
    // full quad sums in every lane (VALU pipe)
    acc0 = quad_sum4(acc0); acc1 = quad_sum4(acc1);
    acc2 = quad_sum4(acc2); acc3 = quad_sum4(acc3);
    acc4 = quad_sum4(acc4); acc5 = quad_sum4(acc5);
    acc6 = quad_sum4(acc6); acc7 = quad_sum4(acc7);
    // lane ks_lo=q emits rows 2q,2q+1 -- CONSTANT-index cndmask select
    // (R4 post-mortem: acc[2*ks_lo] dynamic indexing sent acc[] to scratch)
    float4 s0 = acc0, s1 = acc1;
    if (ks_lo == 1) { s0 = acc2; s1 = acc3; }
    if (ks_lo == 2) { s0 = acc4; s1 = acc5; }
    if (ks_lo == 3) { s0 = acc6; s1 = acc7; }
    {
      const int row0 = rg * 8 + 2 * ks_lo;
      *(float4*)&part[row0 * 33 + ks_hi * 8 + bs * 4] = s0;
      *(float4*)&part[(row0 + 1) * 33 + ks_hi * 8 + bs * 4] = s1;
    }
    __syncthreads();  // B2: part[] complete
    // fused ks_hi-reduce + gates (PyTorch order i,f,g,o) + publish + hist
    if (t < 256) {
      float z0 = xq0, z1 = xq1, z2 = xq2, z3 = xq3;
#pragma unroll
      for (int kq = 0; kq < 4; ++kq) {
        z0 += part[(jj) * 33 + kq * 8 + bg];
        z1 += part[(32 + jj) * 33 + kq * 8 + bg];
        z2 += part[(64 + jj) * 33 + kq * 8 + bg];
        z3 += part[(96 + jj) * 33 + kq * 8 + bg];
      }
      float iv = 1.0f / (1.0f + expf(-z0));
      float fv = 1.0f / (1.0f + expf(-z1));
      float gv = tanhf(z2);
      float ov = 1.0f / (1.0f + expf(-z3));
      c_reg = fv * c_reg + iv * gv;
      float hv = ov * tanhf(c_reg);
      // publish tagged word: [tag = s+1 | h bits], slot = channel*8 + batch
      unsigned long long wv =
          ((unsigned long long)(unsigned)(s + 1) << 32) |
          (unsigned long long)__float_as_uint(hv);
      unsigned long long* bufw = hd + (size_t)(s & 1) * 2048;
      (void)__hip_atomic_exchange(bufw + (size_t)(j0 + jj) * 8 + bg, wv,
                                  __ATOMIC_RELAXED, __HIP_MEMORY_SCOPE_WORKGROUP);
      hist[(size_t)tg * 2048 + bg * Hh + j0 + jj] = hv;
    }
    // no publish-side drain: readers detect tags at the L2 directly
  }
}

// ---------------- feats = [hf|hb] @ W_out^T + b_out ----------------
__global__ __launch_bounds__(256) void k_feats(const float* __restrict__ hist_f,
                                               const float* __restrict__ hist_b,
                                               const float* __restrict__ Wout,
                                               const float* __restrict__ bout,
                                               float* __restrict__ feats) {
  __shared__ float wsh[Tt * 512];
  __shared__ float bsh[Tt];
  for (int i = threadIdx.x; i < Tt * 512; i += 256) wsh[i] = Wout[i];
  if (threadIdx.x < Tt) bsh[threadIdx.x] = bout[threadIdx.x];
  __syncthreads();
  int r = blockIdx.x * 256 + threadIdx.x;
  int bq = r >> 11, sq = r & 2047;
  const float4* hf4 = (const float4*)(hist_f + (size_t)sq * 2048 + bq * Hh);
  const float4* hb4 = (const float4*)(hist_b + (size_t)sq * 2048 + bq * Hh);
  float acc[Tt];
#pragma unroll
  for (int j = 0; j < Tt; ++j) acc[j] = bsh[j];
  for (int k4 = 0; k4 < 64; ++k4) {
    float4 x = hf4[k4];
#pragma unroll
    for (int j = 0; j < Tt; ++j) {
      float4 w = *(const float4*)&wsh[j * 512 + k4 * 4];
      acc[j] = fmaf(x.x, w.x, fmaf(x.y, w.y, fmaf(x.z, w.z, fmaf(x.w, w.w, acc[j]))));
    }
  }
  for (int k4 = 0; k4 < 64; ++k4) {
    float4 x = hb4[k4];
#pragma unroll
    for (int j = 0; j < Tt; ++j) {
      float4 w = *(const float4*)&wsh[j * 512 + 256 + k4 * 4];
      acc[j] = fmaf(x.x, w.x, fmaf(x.y, w.y, fmaf(x.z, w.z, fmaf(x.w, w.w, acc[j]))));
    }
  }
#pragma unroll
  for (int j = 0; j < Tt; ++j) feats[(size_t)r * Tt + j] = acc[j];
}

// ---------------- Viterbi phase 1: per-chunk max-plus matrix product ----------------
__global__ __launch_bounds__(192) void k_vit_chunkmat(const float* __restrict__ feats,
                                                      const float* __restrict__ trans,
                                                      float* __restrict__ pmat) {
  __shared__ float R[2][144];
  __shared__ float fe[LCH * Tt];
  __shared__ float ts[144];
  const int t = threadIdx.x, c = blockIdx.x;
  for (int i = t; i < LCH * Tt; i += 192) fe[i] = feats[(size_t)c * LCH * Tt + i];
  if (t < 144) ts[t] = trans[t];
  __syncthreads();
  int j = 0, k = 0;
  float trow[12];
  if (t < 144) {
    j = t / 12; k = t - j * 12;
#pragma unroll
    for (int m = 0; m < 12; ++m) trow[m] = ts[j * 12 + m];
    R[0][t] = ts[t] + fe[j];  // A_{t0}
  }
  __syncthreads();
  for (int i = 1; i < LCH; ++i) {
    int p = (i - 1) & 1;
    if (t < 144) {
      float m = trow[0] + R[p][k];
#pragma unroll
      for (int mm = 1; mm < 12; ++mm) m = fmaxf(m, trow[mm] + R[p][mm * 12 + k]);
      R[p ^ 1][t] = m + fe[i * 12 + j];
    }
    __syncthreads();
  }
  if (t < 144) pmat[(size_t)c * 144 + t] = R[(LCH - 1) & 1][t];
}

// ---------------- Viterbi phase 2: sequential scan over chunk matrices ----------------
__global__ __launch_bounds__(192) void k_vit_scan(const float* __restrict__ pmat,
                                                  const float* __restrict__ trans,
                                                  float* __restrict__ fvin,
                                                  float* __restrict__ dout,
                                                  int* __restrict__ best) {
  __shared__ float fv[12];
  __shared__ float sl[144];
  __shared__ float term[12];
  const int t = threadIdx.x;
  const int j = t / 12, k = t - j * 12;
  if (t < 12) fv[t] = (t == START_TAG) ? 0.0f : FNEG;
  float pv = (t < 144) ? pmat[t] : 0.0f;
  __syncthreads();
  for (int c = 0; c < NC; ++c) {
    if (t < 12) fvin[c * 12 + t] = fv[t];
    float pnext = (t < 144 && c + 1 < NC) ? pmat[(size_t)(c + 1) * 144 + t] : 0.0f;
    if (t < 144) sl[t] = pv + fv[k];
    __syncthreads();
    if (t < 12) {
      float m = sl[t * 12];
#pragma unroll
      for (int kk = 1; kk < 12; ++kk) m = fmaxf(m, sl[t * 12 + kk]);
      fv[t] = m;
    }
    __syncthreads();
    pv = pnext;
  }
  if (t < 12) term[t] = fv[t] + trans[STOP_TAG * 12 + t];
  __syncthreads();
  if (t == 0) {
    float m = term[0]; int a = 0;
    for (int q = 1; q < 12; ++q) { if (term[q] > m) { m = term[q]; a = q; } }
    dout[0] = m;
    best[0] = a;
  }
}

// ---------------- Viterbi phase 3: replay chunks -> packed backpointers ----------------
__global__ __launch_bounds__(64) void k_vit_replay(const float* __restrict__ feats,
                                                   const float* __restrict__ trans,
                                                   const float* __restrict__ fvin,
                                                   unsigned long long* __restrict__ bptr) {
  __shared__ float fe[LCH * Tt];
  __shared__ float fv[12];
  __shared__ int bpn[12];
  const int t = threadIdx.x, c = blockIdx.x;
  for (int i = t; i < LCH * Tt; i += 64) fe[i] = feats[(size_t)c * LCH * Tt + i];
  float trow[12];
  if (t < 12) {
#pragma unroll
    for (int m = 0; m < 12; ++m) trow[m] = trans[t * 12 + m];
    fv[t] = fvin[c * 12 + t];
  }
  __syncthreads();
  for (int i = 0; i < LCH; ++i) {
    float nm = 0.0f;
    if (t < 12) {
      float m = fv[0] + trow[0]; int a = 0;
#pragma unroll
      for (int k = 1; k < 12; ++k) {
        float v = fv[k] + trow[k];
        if (v > m) { m = v; a = k; }   // first-max wins, matches jnp.argmax
      }
      nm = m + fe[i * 12 + t];
      bpn[t] = a;
    }
    __syncthreads();
    if (t < 12) fv[t] = nm;
    if (t == 0) {
      unsigned long long bp = 0;
#pragma unroll
      for (int jq = 0; jq < 12; ++jq)
        bp |= (unsigned long long)(unsigned)bpn[jq] << (4 * jq);
      bptr[(size_t)c * LCH + i] = bp;
    }
    __syncthreads();
  }
}

// ---------------- backtrace phase A: compose per-chunk tag maps ----------------
__global__ __launch_bounds__(64) void k_bt_chunk(const unsigned long long* __restrict__ bptr,
                                                 int* __restrict__ cmap) {
  __shared__ unsigned long long bp[LCH];
  const int t = threadIdx.x, c = blockIdx.x;
  if (t < LCH) bp[t] = bptr[(size_t)c * LCH + t];
  __syncthreads();
  if (t < 12) {
    int v = t;
    for (int i = LCH - 1; i >= 0; --i) v = (int)((bp[i] >> (4 * v)) & 15ULL);
    cmap[c * 12 + t] = v;
  }
}

// ---------------- backtrace phase B: scan chunk maps ----------------
__global__ __launch_bounds__(256) void k_bt_scan(const int* __restrict__ cmap,
                                                 const int* __restrict__ best,
                                                 int* __restrict__ evec) {
  __shared__ int cm[NC * 12];
  __shared__ int es[NC];
  const int t = threadIdx.x;
  for (int i = t; i < NC * 12; i += 256) cm[i] = cmap[i];
  __syncthreads();
  if (t == 0) {
    int tag = best[0];
    es[NC - 1] = tag;
    for (int c = NC - 1; c >= 1; --c) { tag = cm[c * 12 + tag]; es[c - 1] = tag; }
  }
  __syncthreads();
  evec[t] = es[t];
}

// ---------------- backtrace phase C: emit path ----------------
__global__ __launch_bounds__(64) void k_bt_replay(const unsigned long long* __restrict__ bptr,
                                                  const int* __restrict__ evec,
                                                  float* __restrict__ dout) {
  __shared__ unsigned long long bp[LCH];
  __shared__ int tgs[LCH];
  const int t = threadIdx.x, c = blockIdx.x;
  if (t < LCH) bp[t] = bptr[(size_t)c * LCH + t];
  __syncthreads();
  if (t == 0) {
    int tag = evec[c];  // tag at global index (c+1)*LCH
    for (int i = LCH - 1; i >= 0; --i) {
      tgs[i] = tag;                              // out[c*LCH+i] = tag_{c*LCH+i+1}
      tag = (int)((bp[i] >> (4 * tag)) & 15ULL);
    }
  }
  __syncthreads();
  dout[1 + c * LCH + t] = (float)tgs[t];
}

// ---------------- launcher ----------------
extern "C" void kernel_launch(void* const* d_in, const int* in_sizes, int n_in,
                              void* d_out, int out_size, void* d_ws, size_t ws_size,
                              hipStream_t stream) {
  const int*   sent = (const int*)d_in[0];
  const float* emb  = (const float*)d_in[1];
  const float* wihf = (const float*)d_in[2];
  const float* whhf = (const float*)d_in[3];
  const float* bf   = (const float*)d_in[4];
  const float* wihb = (const float*)d_in[5];
  const float* whhb = (const float*)d_in[6];
  const float* bb   = (const float*)d_in[7];
  const float* h0   = (const float*)d_in[8];
  const float* c0   = (const float*)d_in[9];
  const float* Wout = (const float*)d_in[10];
  const float* bout = (const float*)d_in[11];
  const float* trans= (const float*)d_in[12];
  float* out = (float*)d_out;
  char* ws = (char*)d_ws;
  if (ws_size < WS_NEED) return;  // workspace too small: bail (visible as wrong output)

  float* xs    = (float*)(ws + OFF_XS);
  float* wT    = (float*)(ws + OFF_WT);
  float* xpf   = (float*)(ws + OFF_XPF);
  float* xpb   = (float*)(ws + OFF_XPB);
  float* hf    = (float*)(ws + OFF_HF);
  float* hb    = (float*)(ws + OFF_HB);
  float* feats = (float*)(ws + OFF_FEATS);
  float* pmat  = (float*)(ws + OFF_PMAT);
  float* fvin  = (float*)(ws + OFF_FVIN);
  unsigned long long* bptr = (unsigned long long*)(ws + OFF_BPTR);
  int*   cmap  = (int*)(ws + OFF_CMAP);
  int*   evec  = (int*)(ws + OFF_EVEC);
  int*   best  = (int*)(ws + OFF_BEST);
  unsigned long long* xhd = (unsigned long long*)(ws + OFF_XHD);  // inside feats region
  unsigned* xtk = (unsigned*)(ws + OFF_XTK);

  hipLaunchKernelGGL(k_init, dim3(32), dim3(256), 0, stream, xhd, xtk);
  hipLaunchKernelGGL(k_gather, dim3(512), dim3(256), 0, stream, sent, emb, xs);
  hipLaunchKernelGGL(k_transpose, dim3(2048), dim3(256), 0, stream, wihf, wihb, wT);
  hipLaunchKernelGGL(k_inproj, dim3(512, 8, 2), dim3(256), 0, stream,
                     xs, wT, bf, bb, xpf, xpb);
  hipLaunchKernelGGL(k_lstm, dim3(256), dim3(512), 0, stream,
                     whhf, whhb, h0, c0, xpf, xpb, hf, hb, xhd, xtk, 0ULL);
  hipLaunchKernelGGL(k_feats, dim3(64), dim3(256), 0, stream, hf, hb, Wout, bout, feats);
  hipLaunchKernelGGL(k_vit_chunkmat, dim3(NC), dim3(192), 0, stream, feats, trans, pmat);
  hipLaunchKernelGGL(k_vit_scan, dim3(1), dim3(192), 0, stream, pmat, trans, fvin, out, best);
  hipLaunchKernelGGL(k_vit_replay, dim3(NC), dim3(64), 0, stream, feats, trans, fvin, bptr);
  hipLaunchKernelGGL(k_bt_chunk, dim3(NC), dim3(64), 0, stream, bptr, cmap);
  hipLaunchKernelGGL(k_bt_scan, dim3(1), dim3(256), 0, stream, cmap, best, evec);
  hipLaunchKernelGGL(k_bt_replay, dim3(NC), dim3(64), 0, stream, bptr, evec, out);
}

// Round 5
// 2847.776 us; speedup vs baseline: 10.4076x; 10.4076x over previous
//
#include <hip/hip_runtime.h>
#include <cstdint>
#include <cstddef>

// ---------------- problem constants ----------------
namespace {
constexpr int Bb = 8, Ss = 2048, Ee = 256, Hh = 256, G4 = 1024, Tt = 12;
constexpr int NTOK = Bb * Ss;              // 16384 rows
constexpr int NC = 256, LCH = 64;          // viterbi chunking: 256 chunks x 64 steps
constexpr float FNEG = -10000.0f;
constexpr int START_TAG = 10, STOP_TAG = 11;

// ---------------- workspace layout (bytes) ----------------
constexpr size_t OFF_XS    = 0;                         // [16384][256] f32 gathered embeddings
constexpr size_t SZ_XS     = (size_t)NTOK * Ee * 4;
constexpr size_t OFF_WT    = OFF_XS + SZ_XS;            // [2][256][1024] f32 w_ih transposed
constexpr size_t SZ_WT     = (size_t)2 * Ee * G4 * 4;
constexpr size_t OFF_XPF   = OFF_WT + SZ_WT;            // [2048][8][1024] f32 x-proj fwd (bias folded)
constexpr size_t SZ_XP     = (size_t)Ss * Bb * G4 * 4;
constexpr size_t OFF_XPB   = OFF_XPF + SZ_XP;
constexpr size_t OFF_HF    = OFF_XPB + SZ_XP;           // [2048][8][256] f32 fwd hidden history
constexpr size_t SZ_H      = (size_t)Ss * Bb * Hh * 4;
constexpr size_t OFF_HB    = OFF_HF + SZ_H;
constexpr size_t OFF_FEATS = OFF_HB + SZ_H;             // [16384][12] f32
constexpr size_t SZ_FEATS  = (size_t)NTOK * Tt * 4;
constexpr size_t OFF_PMAT  = OFF_FEATS + SZ_FEATS;      // [256][144] f32 chunk max-plus mats
constexpr size_t SZ_PMAT   = (size_t)NC * 144 * 4;
constexpr size_t OFF_FVIN  = OFF_PMAT + SZ_PMAT;        // [256][12] f32 chunk-entry fv
constexpr size_t SZ_FVIN   = (size_t)NC * Tt * 4;
constexpr size_t OFF_BPTR  = OFF_FVIN + SZ_FVIN;        // [16384] u64 packed 12x4bit backptrs
constexpr size_t SZ_BPTR   = (size_t)NTOK * 8;
constexpr size_t OFF_CMAP  = OFF_BPTR + SZ_BPTR;        // [256][12] int chunk composed maps
constexpr size_t SZ_CMAP   = (size_t)NC * Tt * 4;
constexpr size_t OFF_EVEC  = OFF_CMAP + SZ_CMAP;        // [256] int tag at chunk-end
constexpr size_t SZ_EVEC   = (size_t)NC * 4;
constexpr size_t OFF_BEST  = OFF_EVEC + SZ_EVEC;        // [1] int
constexpr size_t SZ_BEST   = 256;
constexpr size_t OFF_HD    = OFF_BEST + SZ_BEST;        // (legacy MALL exchange buf, unused)
constexpr size_t SZ_HD     = (size_t)2 * 2 * 2048 * 8;
constexpr size_t OFF_CNT   = OFF_HD + SZ_HD;            // (legacy, unused)
constexpr size_t SZ_CNT    = 256;
constexpr size_t WS_NEED   = OFF_CNT + SZ_CNT;          // ~179 MB (unchanged vs prior rounds)

// Per-XCD exchange buffers live INSIDE the feats region (feats is written
// only AFTER k_lstm completes, so the space is dead during the recurrence):
//   xhd: [8 xcd][2 dir][2 par][2048] u64 tagged h   = 512 KB
//   xtk: [8 xcd] u32 arrival tickets, 128B apart    = 1 KB
constexpr size_t OFF_XHD   = OFF_FEATS;
constexpr size_t SZ_XHD    = (size_t)8 * 2 * 2 * 2048 * 8;   // 524288
constexpr size_t OFF_XTK   = OFF_XHD + SZ_XHD;
constexpr size_t SZ_XTK    = 1024;
static_assert(SZ_XHD + SZ_XTK <= SZ_FEATS, "exchange buffers must fit in feats region");

constexpr int POLL_TMO = 1 << 14;   // ~1-2 ms of L2 polls before declaring group dead

__device__ __forceinline__ float4 f4fma(float a, float4 b, float4 c) {
  c.x = fmaf(a, b.x, c.x); c.y = fmaf(a, b.y, c.y);
  c.z = fmaf(a, b.z, c.z); c.w = fmaf(a, b.w, c.w);
  return c;
}

// sum across the 4 lanes of a quad via DPP quad_perm -- VALU pipe only.
__device__ __forceinline__ float quad_sum(float x) {
  float y = __int_as_float(
      __builtin_amdgcn_update_dpp(0, __float_as_int(x), 0xB1, 0xF, 0xF, true));
  x += y;  // + lane^1
  y = __int_as_float(
      __builtin_amdgcn_update_dpp(0, __float_as_int(x), 0x4E, 0xF, 0xF, true));
  return x + y;  // + lane^2
}
__device__ __forceinline__ float4 quad_sum4(float4 v) {
  v.x = quad_sum(v.x); v.y = quad_sum(v.y);
  v.z = quad_sum(v.z); v.w = quad_sum(v.w);
  return v;
}

// R9 L2-point exchange primitives.
// CDNA vector L1 is write-through: a plain global store lands in the XCD's
// shared L2. Loads with the sc0 cache bit BYPASS the (potentially stale)
// per-CU L1 and are served from that same L2 -- normal read path, no atomic
// unit, no MALL visit. R8's counters (23 GB of HBM writebacks from
// fetch_add polls) proved global atomics execute memory-side regardless of
// scope qualifier; these replace them with L2-local plain ops.
__device__ __forceinline__ unsigned long long l2_load_u64(
    const unsigned long long* p) {
  unsigned long long v;
  asm volatile("global_load_dwordx2 %0, %1, off sc0\n\t"
               "s_waitcnt vmcnt(0)"
               : "=v"(v) : "v"(p) : "memory");
  return v;
}
__device__ __forceinline__ void l2_store_u64(unsigned long long* p,
                                             unsigned long long v) {
  asm volatile("global_store_dwordx2 %0, %1, off sc0"
               :: "v"(p), "v"(v) : "memory");
}
}  // namespace

// ---------------- init: zero per-XCD tagged exchange buffers + tickets ----------------
// MUST run each launch/graph-replay: tags are step numbers identical across
// runs; stale tags would satisfy polls with old data. Kernel-end L2 writeback
// makes the zeros visible to k_lstm's sc0 loads on any XCD.
__global__ __launch_bounds__(256) void k_init(unsigned long long* xhd, unsigned* xtk) {
  int g = blockIdx.x * 256 + threadIdx.x;
  for (int i = g; i < 8 * 8192; i += 32 * 256) xhd[i] = 0ULL;
  if (g < 256) xtk[g] = 0u;
}

// ---------------- gather embeddings: xs[r=t*8+b][k] = emb[sentence[b][t]][k] ----------------
__global__ __launch_bounds__(256) void k_gather(const int* __restrict__ sent,
                                                const float* __restrict__ emb,
                                                float* __restrict__ xs) {
  int rr = threadIdx.x >> 3, p = threadIdx.x & 7;
  int r = blockIdx.x * 32 + rr;
  int tg = r >> 3, bg = r & 7;
  int tok = sent[bg * Ss + tg];
  const float4* src = (const float4*)(emb + (size_t)tok * Ee) + p * 8;
  float4* dst = (float4*)(xs + (size_t)r * Ee) + p * 8;
#pragma unroll
  for (int i = 0; i < 8; ++i) dst[i] = src[i];
}

// ---------------- transpose w_ih -> wT[d][k][n] ----------------
__global__ __launch_bounds__(256) void k_transpose(const float* __restrict__ w_f,
                                                   const float* __restrict__ w_b,
                                                   float* __restrict__ wT) {
  int idx = blockIdx.x * 256 + threadIdx.x;
  if (idx >= 2 * Ee * G4) return;
  int d = idx >> 18;
  int rem = idx & 262143;
  int k = rem >> 10, n = rem & 1023;
  const float* w = d ? w_b : w_f;
  wT[idx] = w[n * Ee + k];
}

// ---------------- input projection GEMM: xp[r][n] = xs[r][:] . w_ih[n][:] + bias[n] ----------------
__global__ __launch_bounds__(256) void k_inproj(const float* __restrict__ xs,
                                                const float* __restrict__ wT,
                                                const float* __restrict__ b_f,
                                                const float* __restrict__ b_b,
                                                float* __restrict__ xpf,
                                                float* __restrict__ xpb) {
  const int dir = blockIdx.z;
  const float* wTd = wT + (size_t)dir * (Ee * G4);
  const float* bv = dir ? b_b : b_f;
  float* xp = dir ? xpb : xpf;
  const int rg = threadIdx.x >> 5, cg = threadIdx.x & 31;
  const int rbase = blockIdx.x * 32 + rg * 4;
  const int c0 = blockIdx.y * 128 + cg * 4;
  const float4* ap0 = (const float4*)(xs + (size_t)(rbase + 0) * Ee);
  const float4* ap1 = (const float4*)(xs + (size_t)(rbase + 1) * Ee);
  const float4* ap2 = (const float4*)(xs + (size_t)(rbase + 2) * Ee);
  const float4* ap3 = (const float4*)(xs + (size_t)(rbase + 3) * Ee);
  float4 acc0 = {0,0,0,0}, acc1 = {0,0,0,0}, acc2 = {0,0,0,0}, acc3 = {0,0,0,0};
#pragma unroll 4
  for (int k4 = 0; k4 < 64; ++k4) {
    float4 a0 = ap0[k4], a1 = ap1[k4], a2 = ap2[k4], a3 = ap3[k4];
    const float* wb = wTd + (size_t)(k4 * 4) * G4 + c0;
    float4 b0 = *(const float4*)(wb);
    float4 b1 = *(const float4*)(wb + G4);
    float4 b2 = *(const float4*)(wb + 2 * G4);
    float4 b3 = *(const float4*)(wb + 3 * G4);
    acc0 = f4fma(a0.x, b0, acc0); acc0 = f4fma(a0.y, b1, acc0);
    acc0 = f4fma(a0.z, b2, acc0); acc0 = f4fma(a0.w, b3, acc0);
    acc1 = f4fma(a1.x, b0, acc1); acc1 = f4fma(a1.y, b1, acc1);
    acc1 = f4fma(a1.z, b2, acc1); acc1 = f4fma(a1.w, b3, acc1);
    acc2 = f4fma(a2.x, b0, acc2); acc2 = f4fma(a2.y, b1, acc2);
    acc2 = f4fma(a2.z, b2, acc2); acc2 = f4fma(a2.w, b3, acc2);
    acc3 = f4fma(a3.x, b0, acc3); acc3 = f4fma(a3.y, b1, acc3);
    acc3 = f4fma(a3.z, b2, acc3); acc3 = f4fma(a3.w, b3, acc3);
  }
  float4 bias = *(const float4*)(bv + c0);
  acc0.x += bias.x; acc0.y += bias.y; acc0.z += bias.z; acc0.w += bias.w;
  acc1.x += bias.x; acc1.y += bias.y; acc1.z += bias.z; acc1.w += bias.w;
  acc2.x += bias.x; acc2.y += bias.y; acc2.z += bias.z; acc2.w += bias.w;
  acc3.x += bias.x; acc3.y += bias.y; acc3.z += bias.z; acc3.w += bias.w;
  *(float4*)(xp + (size_t)(rbase + 0) * G4 + c0) = acc0;
  *(float4*)(xp + (size_t)(rbase + 1) * G4 + c0) = acc1;
  *(float4*)(xp + (size_t)(rbase + 2) * G4 + c0) = acc2;
  *(float4*)(xp + (size_t)(rbase + 3) * G4 + c0) = acc3;
}

// ---------------- persistent bidirectional LSTM recurrence ----------------
// R9: SAME-XCD GROUPS (R8 machinery, proven) + L2-POINT sc0 EXCHANGE (new).
//   - 256 blocks; each reads XCC_ID, takes a per-XCD ticket (agent atomic,
//     once at startup). First 16 blocks of each XCD form a complete worker
//     group (wg 0..7 fwd, 8..15 bwd) on that XCD's PRIVATE buffer; later
//     arrivals exit. Pigeonhole guarantees >=1 complete group; all complete
//     groups compute redundantly and write identical hist (benign).
//   - exchange = tag-in-data ([tag:32|f32:32], parity dbuf) via PLAIN
//     write-through stores + sc0 loads (l2_*_u64): producer's store lands in
//     the XCD L2; consumer's sc0 load bypasses its CU L1 and reads that L2.
//     ~200-400cy round trip vs the multi-us MALL hop that R4-R8 all paid
//     (R8 PMC: 26 GB HBM traffic from scope-ignoring atomic polls).
//   - poll timeout: incomplete/miscoherent groups die cleanly without
//     writing (wrong-answer-or-slow, never a hang).
// Starvation-freedom unchanged from R7: a slot polled for tag T holds only
// {0, T-2, T} because overwrite (T -> T+2) requires the writer's whole WG to
// have consumed tag T+1, which requires all readers to have passed tag T.
__global__ __launch_bounds__(512, 2) void k_lstm(
    const float* __restrict__ whh_f, const float* __restrict__ whh_b,
    const float* __restrict__ h0, const float* __restrict__ c0,
    const float* __restrict__ xpf, const float* __restrict__ xpb,
    float* __restrict__ hist_f, float* __restrict__ hist_b,
    unsigned long long* xhd, unsigned* xtk) {
  __shared__ __align__(16) float h_lds[2048];   // [k][b]
  __shared__ float part[128 * 33];              // [row][ks_hi*8 + b], pad 33
  __shared__ int s_role, s_xcc, wg_dead;

  const int t = threadIdx.x;
  if (t == 0) {
    unsigned xcc = __builtin_amdgcn_s_getreg((3 << 11) | 20) & 7u;  // hwreg(XCC_ID=20,0,4)
    unsigned r = __hip_atomic_fetch_add(xtk + xcc * 32, 1u,
                                        __ATOMIC_RELAXED, __HIP_MEMORY_SCOPE_AGENT);
    s_role = (int)r;
    s_xcc = (int)xcc;
    wg_dead = 0;
  }
  __syncthreads();
  if (s_role >= 16) return;   // uniform block exit
  const int wg = s_role, dir = wg >> 3, j0 = (wg & 7) * 32;
  const float* whh = dir ? whh_b : whh_f;
  const float* xp = dir ? xpb : xpf;
  float* hist = dir ? hist_b : hist_f;
  unsigned long long* hd = xhd + (size_t)s_xcc * 8192 + (size_t)dir * 4096;

  // FMA-thread mapping: lane = rg(16) x ks_lo(4); wave = ks_hi(4) x bs(2)
  const int wave = t >> 6, lane = t & 63;
  const int ks_hi = wave & 3, bs = wave >> 2;   // wave-uniform
  const int rg = lane >> 2, ks_lo = lane & 3;   // per-lane
  // weights: 8 rows x 16 k per thread, k = ks_hi*64 + i*4 + ks_lo
  float wreg[8][16];
#pragma unroll
  for (int r = 0; r < 8; ++r) {
    const int row = rg * 8 + r;
    const int n = ((row >> 5) << 8) + j0 + (row & 31);
    const float* wb = whh + (size_t)n * Hh + ks_hi * 64 + ks_lo;
#pragma unroll
    for (int i = 0; i < 16; ++i) wreg[r][i] = wb[i * 4];
  }
  // gate-thread mapping (t<256): owns hidden unit (j0+jj, batch bg)
  const int jj = t >> 3, bg = t & 7;
  float c_reg = 0.0f;
  if (t < 256) c_reg = c0[dir * 2048 + bg * Hh + j0 + jj];

  for (int s = 0; s < Ss; ++s) {
    const int tg = dir ? (Ss - 1 - s) : s;
    // gate threads prefetch their 4 x-proj values (overlap the wait)
    float xq0 = 0.f, xq1 = 0.f, xq2 = 0.f, xq3 = 0.f;
    if (t < 256) {
      const float* xpt = xp + (size_t)tg * 8192 + bg * G4 + j0 + jj;
      xq0 = xpt[0]; xq1 = xpt[256]; xq2 = xpt[512]; xq3 = xpt[768];
    }
    // fill h_lds[k][b] with h_{s-1}
    if (s == 0) {
#pragma unroll
      for (int i = 0; i < 4; ++i) {
        int idx = t * 4 + i;
        h_lds[idx] = h0[dir * 2048 + (idx & 7) * Hh + (idx >> 3)];
      }
    } else {
      // poll own 4 tagged words at the XCD L2 until tag == s
      unsigned long long* buf = hd + (size_t)((s - 1) & 1) * 2048 + 4 * t;
      const unsigned want = (unsigned)s;
      int to = 0;
      unsigned long long w0, w1, w2, w3;
      w0 = l2_load_u64(buf + 0);
      while ((unsigned)(w0 >> 32) != want && ++to < POLL_TMO) {
        __builtin_amdgcn_s_sleep(1);
        w0 = l2_load_u64(buf + 0);
      }
      w1 = l2_load_u64(buf + 1);
      while ((unsigned)(w1 >> 32) != want && ++to < POLL_TMO) {
        __builtin_amdgcn_s_sleep(1);
        w1 = l2_load_u64(buf + 1);
      }
      w2 = l2_load_u64(buf + 2);
      while ((unsigned)(w2 >> 32) != want && ++to < POLL_TMO) {
        __builtin_amdgcn_s_sleep(1);
        w2 = l2_load_u64(buf + 2);
      }
      w3 = l2_load_u64(buf + 3);
      while ((unsigned)(w3 >> 32) != want && ++to < POLL_TMO) {
        __builtin_amdgcn_s_sleep(1);
        w3 = l2_load_u64(buf + 3);
      }
      if (to >= POLL_TMO) wg_dead = 1;
      float4 hv4;
      hv4.x = __uint_as_float((unsigned)w0);
      hv4.y = __uint_as_float((unsigned)w1);
      hv4.z = __uint_as_float((unsigned)w2);
      hv4.w = __uint_as_float((unsigned)w3);
      ((float4*)h_lds)[t] = hv4;
    }
    __syncthreads();  // B1: h_lds ready, prev-step part[] reusable
    if (wg_dead) return;  // dead group: exit before writing anything this step
    // recurrent GEMM: 8 rows x 16 k x 4 b per thread
    float4 acc0 = {0,0,0,0}, acc1 = {0,0,0,0}, acc2 = {0,0,0,0}, acc3 = {0,0,0,0};
    float4 acc4 = {0,0,0,0}, acc5 = {0,0,0,0}, acc6 = {0,0,0,0}, acc7 = {0,0,0,0};
    const float* hbase = h_lds + ks_hi * 512 + ks_lo * 8 + bs * 4;
#pragma unroll
    for (int i = 0; i < 16; ++i) {
      float4 h4 = *(const float4*)(hbase + i * 32);
      acc0 = f4fma(wreg[0][i], h4, acc0);
      acc1 = f4fma(wreg[1][i], h4, acc1);
      acc2 = f4fma(wreg[2][i], h4, acc2);
      acc3 = f4fma(wreg[3][i], h4, acc3);
      acc4 = f4fma(wreg[4][i], h4, acc4);
      acc5 = f4fma(wreg[5][i], h4, acc5);
      acc6 = f4fma(wreg[6][i], h4, acc6);
      acc7 = f4fma(wreg[7][i], h4, acc7);
    }
    // full quad sums in every lane (VALU pipe)
    acc0 = quad_sum4(acc0); acc1 = quad_sum4(acc1);
    acc2 = quad_sum4(acc2); acc3 = quad_sum4(acc3);
    acc4 = quad_sum4(acc4); acc5 = quad_sum4(acc5);
    acc6 = quad_sum4(acc6); acc7 = quad_sum4(acc7);
    // lane ks_lo=q emits rows 2q,2q+1 -- CONSTANT-index cndmask select
    // (R4 post-mortem: acc[2*ks_lo] dynamic indexing sent acc[] to scratch)
    float4 s0 = acc0, s1 = acc1;
    if (ks_lo == 1) { s0 = acc2; s1 = acc3; }
    if (ks_lo == 2) { s0 = acc4; s1 = acc5; }
    if (ks_lo == 3) { s0 = acc6; s1 = acc7; }
    {
      const int row0 = rg * 8 + 2 * ks_lo;
      *(float4*)&part[row0 * 33 + ks_hi * 8 + bs * 4] = s0;
      *(float4*)&part[(row0 + 1) * 33 + ks_hi * 8 + bs * 4] = s1;
    }
    __syncthreads();  // B2: part[] complete
    // fused ks_hi-reduce + gates (PyTorch order i,f,g,o) + publish + hist
    if (t < 256) {
      float z0 = xq0, z1 = xq1, z2 = xq2, z3 = xq3;
#pragma unroll
      for (int kq = 0; kq < 4; ++kq) {
        z0 += part[(jj) * 33 + kq * 8 + bg];
        z1 += part[(32 + jj) * 33 + kq * 8 + bg];
        z2 += part[(64 + jj) * 33 + kq * 8 + bg];
        z3 += part[(96 + jj) * 33 + kq * 8 + bg];
      }
      float iv = 1.0f / (1.0f + expf(-z0));
      float fv = 1.0f / (1.0f + expf(-z1));
      float gv = tanhf(z2);
      float ov = 1.0f / (1.0f + expf(-z3));
      c_reg = fv * c_reg + iv * gv;
      float hv = ov * tanhf(c_reg);
      // publish tagged word: [tag = s+1 | h bits], slot = channel*8 + batch
      unsigned long long wv =
          ((unsigned long long)(unsigned)(s + 1) << 32) |
          (unsigned long long)__float_as_uint(hv);
      unsigned long long* bufw = hd + (size_t)(s & 1) * 2048;
      l2_store_u64(bufw + (size_t)(j0 + jj) * 8 + bg, wv);
      hist[(size_t)tg * 2048 + bg * Hh + j0 + jj] = hv;
    }
    // no publish-side drain: readers detect tags at the XCD L2 directly
  }
}

// ---------------- feats = [hf|hb] @ W_out^T + b_out ----------------
__global__ __launch_bounds__(256) void k_feats(const float* __restrict__ hist_f,
                                               const float* __restrict__ hist_b,
                                               const float* __restrict__ Wout,
                                               const float* __restrict__ bout,
                                               float* __restrict__ feats) {
  __shared__ float wsh[Tt * 512];
  __shared__ float bsh[Tt];
  for (int i = threadIdx.x; i < Tt * 512; i += 256) wsh[i] = Wout[i];
  if (threadIdx.x < Tt) bsh[threadIdx.x] = bout[threadIdx.x];
  __syncthreads();
  int r = blockIdx.x * 256 + threadIdx.x;
  int bq = r >> 11, sq = r & 2047;
  const float4* hf4 = (const float4*)(hist_f + (size_t)sq * 2048 + bq * Hh);
  const float4* hb4 = (const float4*)(hist_b + (size_t)sq * 2048 + bq * Hh);
  float acc[Tt];
#pragma unroll
  for (int j = 0; j < Tt; ++j) acc[j] = bsh[j];
  for (int k4 = 0; k4 < 64; ++k4) {
    float4 x = hf4[k4];
#pragma unroll
    for (int j = 0; j < Tt; ++j) {
      float4 w = *(const float4*)&wsh[j * 512 + k4 * 4];
      acc[j] = fmaf(x.x, w.x, fmaf(x.y, w.y, fmaf(x.z, w.z, fmaf(x.w, w.w, acc[j]))));
    }
  }
  for (int k4 = 0; k4 < 64; ++k4) {
    float4 x = hb4[k4];
#pragma unroll
    for (int j = 0; j < Tt; ++j) {
      float4 w = *(const float4*)&wsh[j * 512 + 256 + k4 * 4];
      acc[j] = fmaf(x.x, w.x, fmaf(x.y, w.y, fmaf(x.z, w.z, fmaf(x.w, w.w, acc[j]))));
    }
  }
#pragma unroll
  for (int j = 0; j < Tt; ++j) feats[(size_t)r * Tt + j] = acc[j];
}

// ---------------- Viterbi phase 1: per-chunk max-plus matrix product ----------------
__global__ __launch_bounds__(192) void k_vit_chunkmat(const float* __restrict__ feats,
                                                      const float* __restrict__ trans,
                                                      float* __restrict__ pmat) {
  __shared__ float R[2][144];
  __shared__ float fe[LCH * Tt];
  __shared__ float ts[144];
  const int t = threadIdx.x, c = blockIdx.x;
  for (int i = t; i < LCH * Tt; i += 192) fe[i] = feats[(size_t)c * LCH * Tt + i];
  if (t < 144) ts[t] = trans[t];
  __syncthreads();
  int j = 0, k = 0;
  float trow[12];
  if (t < 144) {
    j = t / 12; k = t - j * 12;
#pragma unroll
    for (int m = 0; m < 12; ++m) trow[m] = ts[j * 12 + m];
    R[0][t] = ts[t] + fe[j];  // A_{t0}
  }
  __syncthreads();
  for (int i = 1; i < LCH; ++i) {
    int p = (i - 1) & 1;
    if (t < 144) {
      float m = trow[0] + R[p][k];
#pragma unroll
      for (int mm = 1; mm < 12; ++mm) m = fmaxf(m, trow[mm] + R[p][mm * 12 + k]);
      R[p ^ 1][t] = m + fe[i * 12 + j];
    }
    __syncthreads();
  }
  if (t < 144) pmat[(size_t)c * 144 + t] = R[(LCH - 1) & 1][t];
}

// ---------------- Viterbi phase 2: sequential scan over chunk matrices ----------------
__global__ __launch_bounds__(192) void k_vit_scan(const float* __restrict__ pmat,
                                                  const float* __restrict__ trans,
                                                  float* __restrict__ fvin,
                                                  float* __restrict__ dout,
                                                  int* __restrict__ best) {
  __shared__ float fv[12];
  __shared__ float sl[144];
  __shared__ float term[12];
  const int t = threadIdx.x;
  const int j = t / 12, k = t - j * 12;
  if (t < 12) fv[t] = (t == START_TAG) ? 0.0f : FNEG;
  float pv = (t < 144) ? pmat[t] : 0.0f;
  __syncthreads();
  for (int c = 0; c < NC; ++c) {
    if (t < 12) fvin[c * 12 + t] = fv[t];
    float pnext = (t < 144 && c + 1 < NC) ? pmat[(size_t)(c + 1) * 144 + t] : 0.0f;
    if (t < 144) sl[t] = pv + fv[k];
    __syncthreads();
    if (t < 12) {
      float m = sl[t * 12];
#pragma unroll
      for (int kk = 1; kk < 12; ++kk) m = fmaxf(m, sl[t * 12 + kk]);
      fv[t] = m;
    }
    __syncthreads();
    pv = pnext;
  }
  if (t < 12) term[t] = fv[t] + trans[STOP_TAG * 12 + t];
  __syncthreads();
  if (t == 0) {
    float m = term[0]; int a = 0;
    for (int q = 1; q < 12; ++q) { if (term[q] > m) { m = term[q]; a = q; } }
    dout[0] = m;
    best[0] = a;
  }
}

// ---------------- Viterbi phase 3: replay chunks -> packed backpointers ----------------
__global__ __launch_bounds__(64) void k_vit_replay(const float* __restrict__ feats,
                                                   const float* __restrict__ trans,
                                                   const float* __restrict__ fvin,
                                                   unsigned long long* __restrict__ bptr) {
  __shared__ float fe[LCH * Tt];
  __shared__ float fv[12];
  __shared__ int bpn[12];
  const int t = threadIdx.x, c = blockIdx.x;
  for (int i = t; i < LCH * Tt; i += 64) fe[i] = feats[(size_t)c * LCH * Tt + i];
  float trow[12];
  if (t < 12) {
#pragma unroll
    for (int m = 0; m < 12; ++m) trow[m] = trans[t * 12 + m];
    fv[t] = fvin[c * 12 + t];
  }
  __syncthreads();
  for (int i = 0; i < LCH; ++i) {
    float nm = 0.0f;
    if (t < 12) {
      float m = fv[0] + trow[0]; int a = 0;
#pragma unroll
      for (int k = 1; k < 12; ++k) {
        float v = fv[k] + trow[k];
        if (v > m) { m = v; a = k; }   // first-max wins, matches jnp.argmax
      }
      nm = m + fe[i * 12 + t];
      bpn[t] = a;
    }
    __syncthreads();
    if (t < 12) fv[t] = nm;
    if (t == 0) {
      unsigned long long bp = 0;
#pragma unroll
      for (int jq = 0; jq < 12; ++jq)
        bp |= (unsigned long long)(unsigned)bpn[jq] << (4 * jq);
      bptr[(size_t)c * LCH + i] = bp;
    }
    __syncthreads();
  }
}

// ---------------- backtrace phase A: compose per-chunk tag maps ----------------
__global__ __launch_bounds__(64) void k_bt_chunk(const unsigned long long* __restrict__ bptr,
                                                 int* __restrict__ cmap) {
  __shared__ unsigned long long bp[LCH];
  const int t = threadIdx.x, c = blockIdx.x;
  if (t < LCH) bp[t] = bptr[(size_t)c * LCH + t];
  __syncthreads();
  if (t < 12) {
    int v = t;
    for (int i = LCH - 1; i >= 0; --i) v = (int)((bp[i] >> (4 * v)) & 15ULL);
    cmap[c * 12 + t] = v;
  }
}

// ---------------- backtrace phase B: scan chunk maps ----------------
__global__ __launch_bounds__(256) void k_bt_scan(const int* __restrict__ cmap,
                                                 const int* __restrict__ best,
                                                 int* __restrict__ evec) {
  __shared__ int cm[NC * 12];
  __shared__ int es[NC];
  const int t = threadIdx.x;
  for (int i = t; i < NC * 12; i += 256) cm[i] = cmap[i];
  __syncthreads();
  if (t == 0) {
    int tag = best[0];
    es[NC - 1] = tag;
    for (int c = NC - 1; c >= 1; --c) { tag = cm[c * 12 + tag]; es[c - 1] = tag; }
  }
  __syncthreads();
  evec[t] = es[t];
}

// ---------------- backtrace phase C: emit path ----------------
__global__ __launch_bounds__(64) void k_bt_replay(const unsigned long long* __restrict__ bptr,
                                                  const int* __restrict__ evec,
                                                  float* __restrict__ dout) {
  __shared__ unsigned long long bp[LCH];
  __shared__ int tgs[LCH];
  const int t = threadIdx.x, c = blockIdx.x;
  if (t < LCH) bp[t] = bptr[(size_t)c * LCH + t];
  __syncthreads();
  if (t == 0) {
    int tag = evec[c];  // tag at global index (c+1)*LCH
    for (int i = LCH - 1; i >= 0; --i) {
      tgs[i] = tag;                              // out[c*LCH+i] = tag_{c*LCH+i+1}
      tag = (int)((bp[i] >> (4 * tag)) & 15ULL);
    }
  }
  __syncthreads();
  dout[1 + c * LCH + t] = (float)tgs[t];
}

// ---------------- launcher ----------------
extern "C" void kernel_launch(void* const* d_in, const int* in_sizes, int n_in,
                              void* d_out, int out_size, void* d_ws, size_t ws_size,
                              hipStream_t stream) {
  const int*   sent = (const int*)d_in[0];
  const float* emb  = (const float*)d_in[1];
  const float* wihf = (const float*)d_in[2];
  const float* whhf = (const float*)d_in[3];
  const float* bf   = (const float*)d_in[4];
  const float* wihb = (const float*)d_in[5];
  const float* whhb = (const float*)d_in[6];
  const float* bb   = (const float*)d_in[7];
  const float* h0   = (const float*)d_in[8];
  const float* c0   = (const float*)d_in[9];
  const float* Wout = (const float*)d_in[10];
  const float* bout = (const float*)d_in[11];
  const float* trans= (const float*)d_in[12];
  float* out = (float*)d_out;
  char* ws = (char*)d_ws;
  if (ws_size < WS_NEED) return;  // workspace too small: bail (visible as wrong output)

  float* xs    = (float*)(ws + OFF_XS);
  float* wT    = (float*)(ws + OFF_WT);
  float* xpf   = (float*)(ws + OFF_XPF);
  float* xpb   = (float*)(ws + OFF_XPB);
  float* hf    = (float*)(ws + OFF_HF);
  float* hb    = (float*)(ws + OFF_HB);
  float* feats = (float*)(ws + OFF_FEATS);
  float* pmat  = (float*)(ws + OFF_PMAT);
  float* fvin  = (float*)(ws + OFF_FVIN);
  unsigned long long* bptr = (unsigned long long*)(ws + OFF_BPTR);
  int*   cmap  = (int*)(ws + OFF_CMAP);
  int*   evec  = (int*)(ws + OFF_EVEC);
  int*   best  = (int*)(ws + OFF_BEST);
  unsigned long long* xhd = (unsigned long long*)(ws + OFF_XHD);  // inside feats region
  unsigned* xtk = (unsigned*)(ws + OFF_XTK);

  hipLaunchKernelGGL(k_init, dim3(32), dim3(256), 0, stream, xhd, xtk);
  hipLaunchKernelGGL(k_gather, dim3(512), dim3(256), 0, stream, sent, emb, xs);
  hipLaunchKernelGGL(k_transpose, dim3(2048), dim3(256), 0, stream, wihf, wihb, wT);
  hipLaunchKernelGGL(k_inproj, dim3(512, 8, 2), dim3(256), 0, stream,
                     xs, wT, bf, bb, xpf, xpb);
  hipLaunchKernelGGL(k_lstm, dim3(256), dim3(512), 0, stream,
                     whhf, whhb, h0, c0, xpf, xpb, hf, hb, xhd, xtk);
  hipLaunchKernelGGL(k_feats, dim3(64), dim3(256), 0, stream, hf, hb, Wout, bout, feats);
  hipLaunchKernelGGL(k_vit_chunkmat, dim3(NC), dim3(192), 0, stream, feats, trans, pmat);
  hipLaunchKernelGGL(k_vit_scan, dim3(1), dim3(192), 0, stream, pmat, trans, fvin, out, best);
  hipLaunchKernelGGL(k_vit_replay, dim3(NC), dim3(64), 0, stream, feats, trans, fvin, bptr);
  hipLaunchKernelGGL(k_bt_chunk, dim3(NC), dim3(64), 0, stream, bptr, cmap);
  hipLaunchKernelGGL(k_bt_scan, dim3(1), dim3(256), 0, stream, cmap, best, evec);
  hipLaunchKernelGGL(k_bt_replay, dim3(NC), dim3(64), 0, stream, bptr, evec, out);
}